// Round 5
// baseline (1215.205 us; speedup 1.0000x reference)
//
#include <hip/hip_runtime.h>

typedef unsigned short u16;
typedef unsigned int u32;
typedef __attribute__((ext_vector_type(8))) __bf16 bf16x8;
typedef __attribute__((ext_vector_type(4))) float f32x4;
typedef __attribute__((ext_vector_type(4))) u32 u32x4;

// ---------- helpers ----------
__device__ __forceinline__ u16 f2bf(float f) {
  union { float f; u32 u; } v; v.f = f;
  u32 r = v.u + 0x7fffu + ((v.u >> 16) & 1u);   // RNE
  return (u16)(r >> 16);
}
__device__ __forceinline__ float bf2f(u16 h) {
  return __uint_as_float(((u32)h) << 16);
}
__device__ __forceinline__ u32 pk2(float a, float b) {
  return (u32)f2bf(a) | ((u32)f2bf(b) << 16);
}
// async global->LDS, 16B per lane. LDS dest = wave-uniform base + lane*16.
__device__ __forceinline__ void gld16(void* lds, const void* g) {
  __builtin_amdgcn_global_load_lds(
      (__attribute__((address_space(1))) void*)g,
      (__attribute__((address_space(3))) void*)lds, 16, 0, 0);
}

// ---------- X conversion: fp32 -> bf16, 8 elems/thread ----------
__global__ void convert_x(const float* __restrict__ src, u16* __restrict__ dst) {
  const size_t c = (size_t)blockIdx.x * blockDim.x + threadIdx.x;  // chunk of 8
  const float* s = src + c * 8;
  u16 t[8];
#pragma unroll
  for (int i = 0; i < 8; ++i) t[i] = f2bf(s[i]);
  ((uint4*)dst)[c] = *(const uint4*)t;
}

// ---------- weight transpose: src (K x N, fp32) -> dst (N x K, bf16) ----------
__global__ void transpose_w(const float* __restrict__ srcf, u16* __restrict__ dst,
                            int K, int N) {
  __shared__ u16 tile[64][72];
  const int r0 = blockIdx.y * 64, c0 = blockIdx.x * 64;
  const int tr = threadIdx.x >> 2;          // 0..63
  const int tc = (threadIdx.x & 3) * 16;    // 0,16,32,48
  const float* src = srcf + (size_t)(r0 + tr) * N + c0 + tc;
  u16* t = &tile[tr][tc];
#pragma unroll
  for (int i = 0; i < 16; ++i) t[i] = f2bf(src[i]);
  __syncthreads();
  u16 tmp[16];
#pragma unroll
  for (int i = 0; i < 16; ++i) tmp[i] = tile[tc + i][tr];
  uint4* gd = (uint4*)(dst + (size_t)(c0 + tr) * K + r0 + tc);
  gd[0] = *(uint4*)&tmp[0];
  gd[1] = *(uint4*)&tmp[8];
}

// ---------- dual weight transpose (Wk,Wv in one dispatch via grid.z) ----------
__global__ void transpose_w2(const float* __restrict__ s0, u16* __restrict__ d0,
                             const float* __restrict__ s1, u16* __restrict__ d1,
                             int K, int N) {
  __shared__ u16 tile[64][72];
  const float* srcf = blockIdx.z ? s1 : s0;
  u16* dst = blockIdx.z ? d1 : d0;
  const int r0 = blockIdx.y * 64, c0 = blockIdx.x * 64;
  const int tr = threadIdx.x >> 2;
  const int tc = (threadIdx.x & 3) * 16;
  const float* src = srcf + (size_t)(r0 + tr) * N + c0 + tc;
  u16* t = &tile[tr][tc];
#pragma unroll
  for (int i = 0; i < 16; ++i) t[i] = f2bf(src[i]);
  __syncthreads();
  u16 tmp[16];
#pragma unroll
  for (int i = 0; i < 16; ++i) tmp[i] = tile[tc + i][tr];
  uint4* gd = (uint4*)(dst + (size_t)(c0 + tr) * K + r0 + tc);
  gd[0] = *(uint4*)&tmp[0];
  gd[1] = *(uint4*)&tmp[8];
}

// ---------- V transpose: V (b*2048+s, h*128+d) -> Vt[((b*8+h)*128+d)*2048 + s] ----------
__global__ void transpose_v(const u16* __restrict__ V, u16* __restrict__ Vt) {
  __shared__ u16 tile[64][72];
  const int z = blockIdx.z, b = z >> 3, h = z & 7;
  const int s0 = blockIdx.y * 64;   // s tile
  const int d0 = blockIdx.x * 64;   // d tile
  const u16* src = V + ((size_t)(b * 2048 + s0)) * 1024 + h * 128 + d0;
  u16* dst = Vt + ((size_t)((b * 8 + h) * 128 + d0)) * 2048 + s0;
  const int tr = threadIdx.x >> 2;
  const int tc = (threadIdx.x & 3) * 16;
  const uint4* gs = (const uint4*)(src + (size_t)tr * 1024 + tc);
  *(uint4*)&tile[tr][tc] = gs[0];
  *(uint4*)&tile[tr][tc + 8] = gs[1];
  __syncthreads();
  u16 tmp[16];
#pragma unroll
  for (int i = 0; i < 16; ++i) tmp[i] = tile[tc + i][tr];
  uint4* gd = (uint4*)(dst + (size_t)tr * 2048 + tc);
  gd[0] = *(uint4*)&tmp[0];
  gd[1] = *(uint4*)&tmp[8];
}

// ---------- GEMM inner body (m97 structure), shared by both GEMM kernels ----------
template <int OUT32>
__device__ __forceinline__ void gemm_body(
    const u16* A, const u16* Bt, void* Cv, int K, int N, int m0, int n0,
    u16* As, u16* Bs) {
  const int tid = threadIdx.x;
  const int wave = tid >> 6, lane = tid & 63;
  const int wr = (wave >> 1) * 64, wc = (wave & 1) * 64;
  const int lrow = lane & 15, quad = lane >> 4;
  const int cbase = wave * 64 + lane;     // chunk id (16B chunks), r=0

  f32x4 acc[4][4];
#pragma unroll
  for (int i = 0; i < 4; ++i)
#pragma unroll
    for (int j = 0; j < 4; ++j) acc[i][j] = (f32x4){0.f, 0.f, 0.f, 0.f};

  for (int k0 = 0; k0 < K; k0 += 64) {
#pragma unroll
    for (int r = 0; r < 4; ++r) {
      const int c = r * 256 + cbase;          // 0..1023
      const int row = c >> 3, col = (c & 7) * 8;
      gld16(&As[(size_t)(r * 4 + wave) * 512],
            A + (size_t)(m0 + row) * K + k0 + col);
      gld16(&Bs[(size_t)(r * 4 + wave) * 512],
            Bt + (size_t)(n0 + row) * K + k0 + col);
    }
    __syncthreads();   // drains vmcnt(0): tiles resident
#pragma unroll
    for (int kk = 0; kk < 2; ++kk) {
      const int ko = kk * 32 + quad * 8;
      bf16x8 af[4], bfr[4];
#pragma unroll
      for (int i = 0; i < 4; ++i)
        af[i] = *(const bf16x8*)&As[(wr + i * 16 + lrow) * 64 + ko];
#pragma unroll
      for (int j = 0; j < 4; ++j)
        bfr[j] = *(const bf16x8*)&Bs[(wc + j * 16 + lrow) * 64 + ko];
#pragma unroll
      for (int i = 0; i < 4; ++i)
#pragma unroll
        for (int j = 0; j < 4; ++j)
          acc[i][j] = __builtin_amdgcn_mfma_f32_16x16x32_bf16(af[i], bfr[j], acc[i][j], 0, 0, 0);
    }
    __syncthreads();
  }
#pragma unroll
  for (int i = 0; i < 4; ++i)
#pragma unroll
    for (int j = 0; j < 4; ++j)
#pragma unroll
      for (int reg = 0; reg < 4; ++reg) {
        const int row = m0 + wr + i * 16 + quad * 4 + reg;
        const int col = n0 + wc + j * 16 + lrow;
        if (OUT32)
          ((float*)Cv)[(size_t)row * N + col] = acc[i][j][reg];
        else
          ((u16*)Cv)[(size_t)row * N + col] = f2bf(acc[i][j][reg]);
      }
}

// ---------- GEMM: C[M,N] = A[M,K] * Bt^T, tile 128x128 ----------
template <int OUT32>
__global__ __launch_bounds__(256, 2) void gemm_bt128(
    const u16* __restrict__ A, const u16* __restrict__ Bt,
    void* __restrict__ Cv, int K, int N) {
  __shared__ u16 As[128 * 64];
  __shared__ u16 Bs[128 * 64];
  gemm_body<OUT32>(A, Bt, Cv, K, N, blockIdx.y * 128, blockIdx.x * 128, As, Bs);
}

// ---------- fused K+V projection GEMM (one dispatch, 512 blocks = 2/CU) ----------
__global__ __launch_bounds__(256, 2) void gemm_kv(
    const u16* __restrict__ A, const u16* __restrict__ KtW,
    const u16* __restrict__ VtW, u16* __restrict__ Kb, u16* __restrict__ Vb,
    int K, int N) {
  __shared__ u16 As[128 * 64];
  __shared__ u16 Bs[128 * 64];
  const int sel = blockIdx.x >> 3;                 // 0 = K-proj, 1 = V-proj
  const u16* Bt = sel ? VtW : KtW;
  u16* C = sel ? Vb : Kb;
  gemm_body<0>(A, Bt, C, K, N, blockIdx.y * 128, (blockIdx.x & 7) * 128, As, Bs);
}

// ---------- RoPE in-place on Q (4096x4096) and K (4096x1024) ----------
// Q additionally pre-scaled by scale*log2(e) so attn's exp path is exp2(s-m).
__global__ void rope_kernel(u16* __restrict__ Q, u16* __restrict__ Kc) {
  const int row = blockIdx.x;               // b*2048 + s
  const float p = (float)(row & 2047);
  const float csc = 0.088388347762774597f * 1.4426950408889634f;
  for (int t = threadIdx.x; t < 2560; t += 256) {
    u16* base;
    int d;
    float sc;
    if (t < 2048) { const int h = t >> 6; d = t & 63; base = Q + (size_t)row * 4096 + h * 128; sc = csc; }
    else { const int tt = t - 2048; const int h = tt >> 6; d = tt & 63; base = Kc + (size_t)row * 1024 + h * 128; sc = 1.f; }
    const float inv = exp2f((float)d * -0.20762050593046807f);  // 10000^(-d/64)
    const float f = p * inv;
    float s, c;
    sincosf(f, &s, &c);
    const float x1 = bf2f(base[d]);
    const float x2 = bf2f(base[d + 64]);
    base[d] = f2bf((x1 * c - x2 * s) * sc);
    base[d + 64] = f2bf((x2 * c + x1 * s) * sc);
  }
}

// ---------- flash attention ----------
// grid (qtile=16, qhead=32, b=2), 256 threads. Wave owns 32 q-rows.
// KV-tile = 64. Static LDS 34816 B. Q frags in registers.
//
// SWAPPED QK^T: mfma(K,Q) -> lane holds 16 key-values per q-row (q = lane&15).
// KEY-PERMUTED K STAGING: LDS row m holds physical K row
// srcrow(m) = 32*(m>>5) + 8*((m>>2)&3) + 4*((m>>4)&1) + (m&3)  (bit shuffle)
// so each lane's P values ARE its PV B-fragment (register pack only, no P LDS).
// Defer-max (T13, THR=8). XOR-swizzle on staged tiles (rule #21 both-sides).
// Pipelined staging: V(cur) issued at loop top; K(next) after mid barrier.
// Epilogue: O tile staged in LDS (pad 136) then stored as full 16B/lane lines
// to restore L2 write-combining (round-4 counters: 5x write amplification).
__global__ __launch_bounds__(256, 4) void attn(
    const u16* __restrict__ Q, const u16* __restrict__ Kc,
    const u16* __restrict__ Vt, u16* __restrict__ O) {
  __shared__ u16 smem[17408];   // 34816 bytes
  u16* Qs = smem;               // overlay: 128x128 (16384) for initial Q staging
  u16* Ks = smem;               // 64 x 128 (8192 u16)   row=permuted key, col=d
  u16* Vs = smem + 8192;        // 128 x 64 (8192 u16)   row=d, col=key
  u16* Os = smem;               // overlay: 128 x 136 (17408) for epilogue
  const int tid = threadIdx.x, wave = tid >> 6, lane = tid & 63;
  const int qt = blockIdx.x, qh = blockIdx.y, b = blockIdx.z;
  const int kvh = qh >> 2;
  const int lrow = lane & 15, quad = lane >> 4;
  const int swz = (lrow & 7) << 3;          // read-side XOR, element units

  // ---- stage Q tile (128 x 128) via global_load_lds (swizzled source) ----
  const u16* qb = Q + ((size_t)(b * 2048 + qt * 128)) * 4096 + qh * 128;
#pragma unroll
  for (int r = 0; r < 8; ++r) {
    const int c = (r * 4 + wave) * 64 + lane;   // 0..2047 chunks
    const int row = c >> 4, scol = (c & 15) ^ (row & 7);
    gld16(&Qs[(size_t)(r * 4 + wave) * 512],
          qb + (size_t)row * 4096 + scol * 8);
  }
  __syncthreads();
  bf16x8 aq[2][4];
#pragma unroll
  for (int i = 0; i < 2; ++i)
#pragma unroll
    for (int kk = 0; kk < 4; ++kk)
      aq[i][kk] = *(const bf16x8*)
          &Qs[(wave * 32 + i * 16 + lrow) * 128 + ((kk * 32 + quad * 8) ^ swz)];
  __syncthreads();

  // ---- prologue: stage K(0) (permuted rows, swizzled source) ----
  {
    const u16* kb = Kc + ((size_t)(b * 2048)) * 1024 + kvh * 128;
#pragma unroll
    for (int r = 0; r < 4; ++r) {
      const int c = (r * 4 + wave) * 64 + lane;   // 0..1023 chunks
      const int m = c >> 4, scol = (c & 15) ^ (m & 7);
      const int srcrow = ((m >> 5) << 5) | (((m >> 2) & 3) << 3) |
                         (((m >> 4) & 1) << 2) | (m & 3);
      gld16(&Ks[(size_t)(r * 4 + wave) * 512],
            kb + (size_t)srcrow * 1024 + scol * 8);
    }
  }
  __syncthreads();

  // acco[i][j][reg] = O[q = wave*32+i*16+lrow][d = j*16+quad*4+reg]
  f32x4 acco[2][8];
#pragma unroll
  for (int i = 0; i < 2; ++i)
#pragma unroll
    for (int j = 0; j < 8; ++j) acco[i][j] = (f32x4){0.f, 0.f, 0.f, 0.f};
  float m_i[2], l_i[2];
#pragma unroll
  for (int i = 0; i < 2; ++i) { m_i[i] = -INFINITY; l_i[i] = 0.f; }

  const u16* vbase = Vt + ((size_t)((b * 8 + kvh) * 128)) * 2048;

  for (int kv0 = 0; kv0 < 2048; kv0 += 64) {
    // ---- issue V(kv0): 128 d x 64 keys (identity key order); hides under QK^T ----
#pragma unroll
    for (int r = 0; r < 4; ++r) {
      const int c = (r * 4 + wave) * 64 + lane;   // 0..1023 chunks
      const int row = c >> 3, scol = (c & 7) ^ (row & 7);
      gld16(&Vs[(size_t)(r * 4 + wave) * 512],
            vbase + (size_t)row * 2048 + kv0 + scol * 8);
    }

    // ---- S^T = K Q^T: s[i][j][reg] = S[LDS key-row j*16+quad*4+reg][q=lrow] ----
    f32x4 s[2][4];
#pragma unroll
    for (int i = 0; i < 2; ++i)
#pragma unroll
      for (int j = 0; j < 4; ++j) s[i][j] = (f32x4){0.f, 0.f, 0.f, 0.f};
    __builtin_amdgcn_s_setprio(1);
#pragma unroll
    for (int kk = 0; kk < 4; ++kk) {
      const int ko = (kk * 32 + quad * 8) ^ swz;
#pragma unroll
      for (int j = 0; j < 4; ++j) {
        const bf16x8 bk = *(const bf16x8*)&Ks[(j * 16 + lrow) * 128 + ko];
        s[0][j] = __builtin_amdgcn_mfma_f32_16x16x32_bf16(bk, aq[0][kk], s[0][j], 0, 0, 0);
        s[1][j] = __builtin_amdgcn_mfma_f32_16x16x32_bf16(bk, aq[1][kk], s[1][j], 0, 0, 0);
      }
    }
    __builtin_amdgcn_s_setprio(0);

    // ---- online softmax: per q-group, in-lane reduce + 2 shuffles ----
#pragma unroll
    for (int i = 0; i < 2; ++i) {
      float mx = s[i][0][0];
#pragma unroll
      for (int j = 0; j < 4; ++j)
#pragma unroll
        for (int reg = 0; reg < 4; ++reg) mx = fmaxf(mx, s[i][j][reg]);
      mx = fmaxf(mx, __shfl_xor(mx, 16));
      mx = fmaxf(mx, __shfl_xor(mx, 32));
      const bool grow = !__all(mx <= m_i[i] + 8.f);   // defer-max THR=8
      float mnew = m_i[i], al = 1.f;
      if (grow) {
        mnew = fmaxf(m_i[i], mx);
        al = exp2f(m_i[i] - mnew);
        m_i[i] = mnew;
      }
      float rs = 0.f;
#pragma unroll
      for (int j = 0; j < 4; ++j)
#pragma unroll
        for (int reg = 0; reg < 4; ++reg) {
          const float p0 = exp2f(s[i][j][reg] - mnew);
          s[i][j][reg] = p0;
          rs += p0;
        }
      rs += __shfl_xor(rs, 16);
      rs += __shfl_xor(rs, 32);
      l_i[i] = l_i[i] * al + rs;
      if (grow) {
#pragma unroll
        for (int j = 0; j < 8; ++j)
#pragma unroll
          for (int reg = 0; reg < 4; ++reg) acco[i][j][reg] *= al;
      }
    }

    // ---- pack P into PV B-fragments (register only; key-permute makes this exact) ----
    u32x4 pw[2][2];
#pragma unroll
    for (int i = 0; i < 2; ++i)
#pragma unroll
      for (int kk = 0; kk < 2; ++kk) {
        pw[i][kk].x = pk2(s[i][2 * kk][0], s[i][2 * kk][1]);
        pw[i][kk].y = pk2(s[i][2 * kk][2], s[i][2 * kk][3]);
        pw[i][kk].z = pk2(s[i][2 * kk + 1][0], s[i][2 * kk + 1][1]);
        pw[i][kk].w = pk2(s[i][2 * kk + 1][2], s[i][2 * kk + 1][3]);
      }
    __syncthreads();   // drains V loads; all waves past QK^T (Ks free)

    // ---- issue K(kv0+64) (permuted rows, swizzled source): hides under PV ----
    if (kv0 + 64 < 2048) {
      const u16* kb = Kc + ((size_t)(b * 2048 + kv0 + 64)) * 1024 + kvh * 128;
#pragma unroll
      for (int r = 0; r < 4; ++r) {
        const int c = (r * 4 + wave) * 64 + lane;
        const int m = c >> 4, scol = (c & 15) ^ (m & 7);
        const int srcrow = ((m >> 5) << 5) | (((m >> 2) & 3) << 3) |
                           (((m >> 4) & 1) << 2) | (m & 3);
        gld16(&Ks[(size_t)(r * 4 + wave) * 512],
              kb + (size_t)srcrow * 1024 + scol * 8);
      }
    }

    // ---- O^T += V P^T: A = V-frag from LDS, B = P-frag from registers ----
    __builtin_amdgcn_s_setprio(1);
#pragma unroll
    for (int kk = 0; kk < 2; ++kk) {
      const int kov = (kk * 32 + quad * 8) ^ swz;
      const bf16x8 ap0 = __builtin_bit_cast(bf16x8, pw[0][kk]);
      const bf16x8 ap1 = __builtin_bit_cast(bf16x8, pw[1][kk]);
#pragma unroll
      for (int j = 0; j < 8; ++j) {
        const bf16x8 bv = *(const bf16x8*)&Vs[(j * 16 + lrow) * 64 + kov];
        acco[0][j] = __builtin_amdgcn_mfma_f32_16x16x32_bf16(bv, ap0, acco[0][j], 0, 0, 0);
        acco[1][j] = __builtin_amdgcn_mfma_f32_16x16x32_bf16(bv, ap1, acco[1][j], 0, 0, 0);
      }
    }
    __builtin_amdgcn_s_setprio(0);
    __syncthreads();   // drains K(next) prefetch; PV reads of Vs complete
  }

  // ---- epilogue: stage O tile in LDS, then full-line coalesced stores ----
#pragma unroll
  for (int i = 0; i < 2; ++i) {
    const float inv = 1.0f / l_i[i];
    const int rl = wave * 32 + i * 16 + lrow;        // local row 0..127
#pragma unroll
    for (int j = 0; j < 8; ++j) {
      u16 t4[4];
#pragma unroll
      for (int reg = 0; reg < 4; ++reg) t4[reg] = f2bf(acco[i][j][reg] * inv);
      *(uint2*)&Os[rl * 136 + j * 16 + quad * 4] = *(const uint2*)t4;
    }
  }
  __syncthreads();
  const u16* obase = O + ((size_t)(b * 2048 + qt * 128)) * 4096 + qh * 128;
#pragma unroll
  for (int r = 0; r < 8; ++r) {
    const int chunk = r * 256 + tid;                 // 0..2047 (16B chunks)
    const int row = chunk >> 4, col = (chunk & 15) * 8;
    *(uint4*)(const_cast<u16*>(obase) + (size_t)row * 4096 + col) =
        *(const uint4*)&Os[row * 136 + col];
  }
}

// ---------- launch ----------
extern "C" void kernel_launch(void* const* d_in, const int* in_sizes, int n_in,
                              void* d_out, int out_size, void* d_ws, size_t ws_size,
                              hipStream_t stream) {
  const float* X  = (const float*)d_in[0];
  const float* Wq = (const float*)d_in[2];
  const float* Wk = (const float*)d_in[3];
  const float* Wv = (const float*)d_in[4];
  const float* Wo = (const float*)d_in[5];
  u16* ws = (u16*)d_ws;

  // workspace (u16 elements), ~126 MiB total:
  // Xb(16.7M) | R0(16.7M) | R1(16.7M) | R2(4.2M) | R3(4.2M) | R4(4.2M)
  u16* Xb = ws;
  u16* R0 = Xb + 16777216;
  u16* R1 = R0 + 16777216;
  u16* R2 = R1 + 16777216;
  u16* R3 = R2 + 4194304;
  u16* R4 = R3 + 4194304;
  u16* Qb = R1, *Kb = R3, *Vb = R4, *Vt = R2, *Ob = R0, *WoT = R1;
  u16* WkT = R0;                 // 1024x4096 bf16 (4.2M u16)
  u16* WvT = R0 + 4194304;       // 1024x4096 bf16 (4.2M u16)

  convert_x<<<8192, 256, 0, stream>>>(X, Xb);

  transpose_w<<<dim3(64, 64), 256, 0, stream>>>(Wq, R0, 4096, 4096);
  gemm_bt128<0><<<dim3(32, 32), 256, 0, stream>>>(Xb, R0, Qb, 4096, 4096);

  transpose_w2<<<dim3(16, 64, 2), 256, 0, stream>>>(Wk, WkT, Wv, WvT, 4096, 1024);
  gemm_kv<<<dim3(16, 32), 256, 0, stream>>>(Xb, WkT, WvT, Kb, Vb, 4096, 1024);

  rope_kernel<<<4096, 256, 0, stream>>>(Qb, Kb);
  transpose_v<<<dim3(2, 32, 16), 256, 0, stream>>>(Vb, Vt);

  attn<<<dim3(16, 32, 2), 256, 0, stream>>>(Qb, Kb, Vt, Ob);

  transpose_w<<<dim3(64, 64), 256, 0, stream>>>(Wo, WoT, 4096, 4096);
  gemm_bt128<1><<<dim3(32, 32), 256, 0, stream>>>(Ob, WoT, d_out, 4096, 4096);
}

// Round 6
// 939.773 us; speedup vs baseline: 1.2931x; 1.2931x over previous
//
#include <hip/hip_runtime.h>

typedef unsigned short u16;
typedef unsigned int u32;
typedef __attribute__((ext_vector_type(8))) __bf16 bf16x8;
typedef __attribute__((ext_vector_type(4))) float f32x4;
typedef __attribute__((ext_vector_type(4))) u32 u32x4;

// ---------- helpers ----------
__device__ __forceinline__ u16 f2bf(float f) {
  union { float f; u32 u; } v; v.f = f;
  u32 r = v.u + 0x7fffu + ((v.u >> 16) & 1u);   // RNE
  return (u16)(r >> 16);
}
__device__ __forceinline__ float bf2f(u16 h) {
  return __uint_as_float(((u32)h) << 16);
}
__device__ __forceinline__ u32 pk2(float a, float b) {
  return (u32)f2bf(a) | ((u32)f2bf(b) << 16);
}
// async global->LDS, 16B per lane. LDS dest = wave-uniform base + lane*16.
__device__ __forceinline__ void gld16(void* lds, const void* g) {
  __builtin_amdgcn_global_load_lds(
      (__attribute__((address_space(1))) void*)g,
      (__attribute__((address_space(3))) void*)lds, 16, 0, 0);
}

// ---------- X conversion: fp32 -> bf16, 8 elems/thread ----------
__global__ void convert_x(const float* __restrict__ src, u16* __restrict__ dst) {
  const size_t c = (size_t)blockIdx.x * blockDim.x + threadIdx.x;  // chunk of 8
  const float* s = src + c * 8;
  u16 t[8];
#pragma unroll
  for (int i = 0; i < 8; ++i) t[i] = f2bf(s[i]);
  ((uint4*)dst)[c] = *(const uint4*)t;
}

// ---------- weight transpose: src (K x N, fp32) -> dst (N x K, bf16) ----------
__global__ void transpose_w(const float* __restrict__ srcf, u16* __restrict__ dst,
                            int K, int N) {
  __shared__ u16 tile[64][72];
  const int r0 = blockIdx.y * 64, c0 = blockIdx.x * 64;
  const int tr = threadIdx.x >> 2;          // 0..63
  const int tc = (threadIdx.x & 3) * 16;    // 0,16,32,48
  const float* src = srcf + (size_t)(r0 + tr) * N + c0 + tc;
  u16* t = &tile[tr][tc];
#pragma unroll
  for (int i = 0; i < 16; ++i) t[i] = f2bf(src[i]);
  __syncthreads();
  u16 tmp[16];
#pragma unroll
  for (int i = 0; i < 16; ++i) tmp[i] = tile[tc + i][tr];
  uint4* gd = (uint4*)(dst + (size_t)(c0 + tr) * K + r0 + tc);
  gd[0] = *(uint4*)&tmp[0];
  gd[1] = *(uint4*)&tmp[8];
}

// ---------- dual weight transpose (Wk,Wv in one dispatch via grid.z) ----------
__global__ void transpose_w2(const float* __restrict__ s0, u16* __restrict__ d0,
                             const float* __restrict__ s1, u16* __restrict__ d1,
                             int K, int N) {
  __shared__ u16 tile[64][72];
  const float* srcf = blockIdx.z ? s1 : s0;
  u16* dst = blockIdx.z ? d1 : d0;
  const int r0 = blockIdx.y * 64, c0 = blockIdx.x * 64;
  const int tr = threadIdx.x >> 2;
  const int tc = (threadIdx.x & 3) * 16;
  const float* src = srcf + (size_t)(r0 + tr) * N + c0 + tc;
  u16* t = &tile[tr][tc];
#pragma unroll
  for (int i = 0; i < 16; ++i) t[i] = f2bf(src[i]);
  __syncthreads();
  u16 tmp[16];
#pragma unroll
  for (int i = 0; i < 16; ++i) tmp[i] = tile[tc + i][tr];
  uint4* gd = (uint4*)(dst + (size_t)(c0 + tr) * K + r0 + tc);
  gd[0] = *(uint4*)&tmp[0];
  gd[1] = *(uint4*)&tmp[8];
}

// ---------- V transpose: V (b*2048+s, h*128+d) -> Vt[((b*8+h)*128+d)*2048 + s] ----------
__global__ void transpose_v(const u16* __restrict__ V, u16* __restrict__ Vt) {
  __shared__ u16 tile[64][72];
  const int z = blockIdx.z, b = z >> 3, h = z & 7;
  const int s0 = blockIdx.y * 64;   // s tile
  const int d0 = blockIdx.x * 64;   // d tile
  const u16* src = V + ((size_t)(b * 2048 + s0)) * 1024 + h * 128 + d0;
  u16* dst = Vt + ((size_t)((b * 8 + h) * 128 + d0)) * 2048 + s0;
  const int tr = threadIdx.x >> 2;
  const int tc = (threadIdx.x & 3) * 16;
  const uint4* gs = (const uint4*)(src + (size_t)tr * 1024 + tc);
  *(uint4*)&tile[tr][tc] = gs[0];
  *(uint4*)&tile[tr][tc + 8] = gs[1];
  __syncthreads();
  u16 tmp[16];
#pragma unroll
  for (int i = 0; i < 16; ++i) tmp[i] = tile[tc + i][tr];
  uint4* gd = (uint4*)(dst + (size_t)tr * 2048 + tc);
  gd[0] = *(uint4*)&tmp[0];
  gd[1] = *(uint4*)&tmp[8];
}

// ---------- GEMM inner body (m97 structure), shared by both GEMM kernels ----------
template <int OUT32>
__device__ __forceinline__ void gemm_body(
    const u16* A, const u16* Bt, void* Cv, int K, int N, int m0, int n0,
    u16* As, u16* Bs) {
  const int tid = threadIdx.x;
  const int wave = tid >> 6, lane = tid & 63;
  const int wr = (wave >> 1) * 64, wc = (wave & 1) * 64;
  const int lrow = lane & 15, quad = lane >> 4;
  const int cbase = wave * 64 + lane;     // chunk id (16B chunks), r=0

  f32x4 acc[4][4];
#pragma unroll
  for (int i = 0; i < 4; ++i)
#pragma unroll
    for (int j = 0; j < 4; ++j) acc[i][j] = (f32x4){0.f, 0.f, 0.f, 0.f};

  for (int k0 = 0; k0 < K; k0 += 64) {
#pragma unroll
    for (int r = 0; r < 4; ++r) {
      const int c = r * 256 + cbase;          // 0..1023
      const int row = c >> 3, col = (c & 7) * 8;
      gld16(&As[(size_t)(r * 4 + wave) * 512],
            A + (size_t)(m0 + row) * K + k0 + col);
      gld16(&Bs[(size_t)(r * 4 + wave) * 512],
            Bt + (size_t)(n0 + row) * K + k0 + col);
    }
    __syncthreads();   // drains vmcnt(0): tiles resident
#pragma unroll
    for (int kk = 0; kk < 2; ++kk) {
      const int ko = kk * 32 + quad * 8;
      bf16x8 af[4], bfr[4];
#pragma unroll
      for (int i = 0; i < 4; ++i)
        af[i] = *(const bf16x8*)&As[(wr + i * 16 + lrow) * 64 + ko];
#pragma unroll
      for (int j = 0; j < 4; ++j)
        bfr[j] = *(const bf16x8*)&Bs[(wc + j * 16 + lrow) * 64 + ko];
#pragma unroll
      for (int i = 0; i < 4; ++i)
#pragma unroll
        for (int j = 0; j < 4; ++j)
          acc[i][j] = __builtin_amdgcn_mfma_f32_16x16x32_bf16(af[i], bfr[j], acc[i][j], 0, 0, 0);
    }
    __syncthreads();
  }
#pragma unroll
  for (int i = 0; i < 4; ++i)
#pragma unroll
    for (int j = 0; j < 4; ++j)
#pragma unroll
      for (int reg = 0; reg < 4; ++reg) {
        const int row = m0 + wr + i * 16 + quad * 4 + reg;
        const int col = n0 + wc + j * 16 + lrow;
        if (OUT32)
          ((float*)Cv)[(size_t)row * N + col] = acc[i][j][reg];
        else
          ((u16*)Cv)[(size_t)row * N + col] = f2bf(acc[i][j][reg]);
      }
}

// ---------- GEMM: C[M,N] = A[M,K] * Bt^T, tile 128x128 ----------
template <int OUT32>
__global__ __launch_bounds__(256, 2) void gemm_bt128(
    const u16* __restrict__ A, const u16* __restrict__ Bt,
    void* __restrict__ Cv, int K, int N) {
  __shared__ u16 As[128 * 64];
  __shared__ u16 Bs[128 * 64];
  gemm_body<OUT32>(A, Bt, Cv, K, N, blockIdx.y * 128, blockIdx.x * 128, As, Bs);
}

// ---------- fused K+V projection GEMM (one dispatch, 512 blocks = 2/CU) ----------
__global__ __launch_bounds__(256, 2) void gemm_kv(
    const u16* __restrict__ A, const u16* __restrict__ KtW,
    const u16* __restrict__ VtW, u16* __restrict__ Kb, u16* __restrict__ Vb,
    int K, int N) {
  __shared__ u16 As[128 * 64];
  __shared__ u16 Bs[128 * 64];
  const int sel = blockIdx.x >> 3;                 // 0 = K-proj, 1 = V-proj
  const u16* Bt = sel ? VtW : KtW;
  u16* C = sel ? Vb : Kb;
  gemm_body<0>(A, Bt, C, K, N, blockIdx.y * 128, (blockIdx.x & 7) * 128, As, Bs);
}

// ---------- RoPE in-place on Q (4096x4096) and K (4096x1024) ----------
// Q additionally pre-scaled by scale*log2(e) so attn's exp path is exp2(s-m).
__global__ void rope_kernel(u16* __restrict__ Q, u16* __restrict__ Kc) {
  const int row = blockIdx.x;               // b*2048 + s
  const float p = (float)(row & 2047);
  const float csc = 0.088388347762774597f * 1.4426950408889634f;
  for (int t = threadIdx.x; t < 2560; t += 256) {
    u16* base;
    int d;
    float sc;
    if (t < 2048) { const int h = t >> 6; d = t & 63; base = Q + (size_t)row * 4096 + h * 128; sc = csc; }
    else { const int tt = t - 2048; const int h = tt >> 6; d = tt & 63; base = Kc + (size_t)row * 1024 + h * 128; sc = 1.f; }
    const float inv = exp2f((float)d * -0.20762050593046807f);  // 10000^(-d/64)
    const float f = p * inv;
    float s, c;
    sincosf(f, &s, &c);
    const float x1 = bf2f(base[d]);
    const float x2 = bf2f(base[d + 64]);
    base[d] = f2bf((x1 * c - x2 * s) * sc);
    base[d + 64] = f2bf((x2 * c + x1 * s) * sc);
  }
}

// ---------- flash attention ----------
// flat grid 1024 blocks, 256 threads. Wave owns 32 q-rows. KV-tile = 64.
//
// XCD-LOCALITY REMAP (round-6 fix): HW round-robins blocks over 8 XCDs
// (xcd = flat%8). All 64 blocks of one (kvh,b) supergroup share the same
// 1 MB K/V stream, so we invert the round-robin to pin each supergroup to
// ONE XCD (2 supergroups = 2 MB per 4 MB L2):
//   flat = xcd + 8*slot; sg = (slot>>6)*8 + xcd; inner = slot&63
//   kvh = sg>>1; b = sg&1; qh = kvh*4 + (inner>>4); qt = inner&15
// Round-5 counters without this: FETCH 1.24 GB / WRITE 1.0 GB (L2 thrash).
// Co-residency capped at 3 blocks/CU (round-4 measured-good point) -- at 4,
// the whole grid is resident and even remapped streams overflow L2.
//
// SWAPPED QK^T: mfma(K,Q) -> lane holds 16 key-values per q-row (q = lane&15).
// KEY-PERMUTED K STAGING: LDS row m holds physical K row
// srcrow(m) = 32*(m>>5) + 8*((m>>2)&3) + 4*((m>>4)&1) + (m&3) so each lane's
// P values ARE its PV B-fragment (register pack only, no P LDS buffer).
// Defer-max (T13, THR=8). XOR-swizzle on staged tiles (rule #21 both-sides).
// Pipelined staging: V(cur) issued at loop top; K(next) after mid barrier.
// Epilogue: O tile staged in LDS (pad 136) then full 16B/lane line stores.
__global__ __launch_bounds__(256, 3) void attn(
    const u16* __restrict__ Q, const u16* __restrict__ Kc,
    const u16* __restrict__ Vt, u16* __restrict__ O) {
  __shared__ u16 smem[17408];   // 34816 bytes
  u16* Qs = smem;               // overlay: 128x128 (16384) for initial Q staging
  u16* Ks = smem;               // 64 x 128 (8192 u16)   row=permuted key, col=d
  u16* Vs = smem + 8192;        // 128 x 64 (8192 u16)   row=d, col=key
  u16* Os = smem;               // overlay: 128 x 136 (17408) for epilogue
  const int tid = threadIdx.x, wave = tid >> 6, lane = tid & 63;
  // ---- XCD-locality decode ----
  const int fid = blockIdx.x;                 // 0..1023
  const int xcd = fid & 7, slot = fid >> 3;   // slot 0..127
  const int sg = ((slot >> 6) << 3) | xcd;    // supergroup = kvh*2 + b, 0..15
  const int kvh = sg >> 1, b = sg & 1;
  const int inner = slot & 63;
  const int qh = kvh * 4 + (inner >> 4);
  const int qt = inner & 15;
  const int lrow = lane & 15, quad = lane >> 4;
  const int swz = (lrow & 7) << 3;          // read-side XOR, element units

  // ---- stage Q tile (128 x 128) via global_load_lds (swizzled source) ----
  const u16* qb = Q + ((size_t)(b * 2048 + qt * 128)) * 4096 + qh * 128;
#pragma unroll
  for (int r = 0; r < 8; ++r) {
    const int c = (r * 4 + wave) * 64 + lane;   // 0..2047 chunks
    const int row = c >> 4, scol = (c & 15) ^ (row & 7);
    gld16(&Qs[(size_t)(r * 4 + wave) * 512],
          qb + (size_t)row * 4096 + scol * 8);
  }
  __syncthreads();
  bf16x8 aq[2][4];
#pragma unroll
  for (int i = 0; i < 2; ++i)
#pragma unroll
    for (int kk = 0; kk < 4; ++kk)
      aq[i][kk] = *(const bf16x8*)
          &Qs[(wave * 32 + i * 16 + lrow) * 128 + ((kk * 32 + quad * 8) ^ swz)];
  __syncthreads();

  // ---- prologue: stage K(0) (permuted rows, swizzled source) ----
  {
    const u16* kb = Kc + ((size_t)(b * 2048)) * 1024 + kvh * 128;
#pragma unroll
    for (int r = 0; r < 4; ++r) {
      const int c = (r * 4 + wave) * 64 + lane;   // 0..1023 chunks
      const int m = c >> 4, scol = (c & 15) ^ (m & 7);
      const int srcrow = ((m >> 5) << 5) | (((m >> 2) & 3) << 3) |
                         (((m >> 4) & 1) << 2) | (m & 3);
      gld16(&Ks[(size_t)(r * 4 + wave) * 512],
            kb + (size_t)srcrow * 1024 + scol * 8);
    }
  }
  __syncthreads();

  // acco[i][j][reg] = O[q = wave*32+i*16+lrow][d = j*16+quad*4+reg]
  f32x4 acco[2][8];
#pragma unroll
  for (int i = 0; i < 2; ++i)
#pragma unroll
    for (int j = 0; j < 8; ++j) acco[i][j] = (f32x4){0.f, 0.f, 0.f, 0.f};
  float m_i[2], l_i[2];
#pragma unroll
  for (int i = 0; i < 2; ++i) { m_i[i] = -INFINITY; l_i[i] = 0.f; }

  const u16* vbase = Vt + ((size_t)((b * 8 + kvh) * 128)) * 2048;

  for (int kv0 = 0; kv0 < 2048; kv0 += 64) {
    // ---- issue V(kv0): 128 d x 64 keys (identity key order); hides under QK^T ----
#pragma unroll
    for (int r = 0; r < 4; ++r) {
      const int c = (r * 4 + wave) * 64 + lane;   // 0..1023 chunks
      const int row = c >> 3, scol = (c & 7) ^ (row & 7);
      gld16(&Vs[(size_t)(r * 4 + wave) * 512],
            vbase + (size_t)row * 2048 + kv0 + scol * 8);
    }

    // ---- S^T = K Q^T: s[i][j][reg] = S[LDS key-row j*16+quad*4+reg][q=lrow] ----
    f32x4 s[2][4];
#pragma unroll
    for (int i = 0; i < 2; ++i)
#pragma unroll
      for (int j = 0; j < 4; ++j) s[i][j] = (f32x4){0.f, 0.f, 0.f, 0.f};
    __builtin_amdgcn_s_setprio(1);
#pragma unroll
    for (int kk = 0; kk < 4; ++kk) {
      const int ko = (kk * 32 + quad * 8) ^ swz;
#pragma unroll
      for (int j = 0; j < 4; ++j) {
        const bf16x8 bk = *(const bf16x8*)&Ks[(j * 16 + lrow) * 128 + ko];
        s[0][j] = __builtin_amdgcn_mfma_f32_16x16x32_bf16(bk, aq[0][kk], s[0][j], 0, 0, 0);
        s[1][j] = __builtin_amdgcn_mfma_f32_16x16x32_bf16(bk, aq[1][kk], s[1][j], 0, 0, 0);
      }
    }
    __builtin_amdgcn_s_setprio(0);

    // ---- online softmax: per q-group, in-lane reduce + 2 shuffles ----
#pragma unroll
    for (int i = 0; i < 2; ++i) {
      float mx = s[i][0][0];
#pragma unroll
      for (int j = 0; j < 4; ++j)
#pragma unroll
        for (int reg = 0; reg < 4; ++reg) mx = fmaxf(mx, s[i][j][reg]);
      mx = fmaxf(mx, __shfl_xor(mx, 16));
      mx = fmaxf(mx, __shfl_xor(mx, 32));
      const bool grow = !__all(mx <= m_i[i] + 8.f);   // defer-max THR=8
      float mnew = m_i[i], al = 1.f;
      if (grow) {
        mnew = fmaxf(m_i[i], mx);
        al = exp2f(m_i[i] - mnew);
        m_i[i] = mnew;
      }
      float rs = 0.f;
#pragma unroll
      for (int j = 0; j < 4; ++j)
#pragma unroll
        for (int reg = 0; reg < 4; ++reg) {
          const float p0 = exp2f(s[i][j][reg] - mnew);
          s[i][j][reg] = p0;
          rs += p0;
        }
      rs += __shfl_xor(rs, 16);
      rs += __shfl_xor(rs, 32);
      l_i[i] = l_i[i] * al + rs;
      if (grow) {
#pragma unroll
        for (int j = 0; j < 8; ++j)
#pragma unroll
          for (int reg = 0; reg < 4; ++reg) acco[i][j][reg] *= al;
      }
    }

    // ---- pack P into PV B-fragments (register only; key-permute makes this exact) ----
    u32x4 pw[2][2];
#pragma unroll
    for (int i = 0; i < 2; ++i)
#pragma unroll
      for (int kk = 0; kk < 2; ++kk) {
        pw[i][kk].x = pk2(s[i][2 * kk][0], s[i][2 * kk][1]);
        pw[i][kk].y = pk2(s[i][2 * kk][2], s[i][2 * kk][3]);
        pw[i][kk].z = pk2(s[i][2 * kk + 1][0], s[i][2 * kk + 1][1]);
        pw[i][kk].w = pk2(s[i][2 * kk + 1][2], s[i][2 * kk + 1][3]);
      }
    __syncthreads();   // drains V loads; all waves past QK^T (Ks free)

    // ---- issue K(kv0+64) (permuted rows, swizzled source): hides under PV ----
    if (kv0 + 64 < 2048) {
      const u16* kb = Kc + ((size_t)(b * 2048 + kv0 + 64)) * 1024 + kvh * 128;
#pragma unroll
      for (int r = 0; r < 4; ++r) {
        const int c = (r * 4 + wave) * 64 + lane;
        const int m = c >> 4, scol = (c & 15) ^ (m & 7);
        const int srcrow = ((m >> 5) << 5) | (((m >> 2) & 3) << 3) |
                           (((m >> 4) & 1) << 2) | (m & 3);
        gld16(&Ks[(size_t)(r * 4 + wave) * 512],
              kb + (size_t)srcrow * 1024 + scol * 8);
      }
    }

    // ---- O^T += V P^T: A = V-frag from LDS, B = P-frag from registers ----
    __builtin_amdgcn_s_setprio(1);
#pragma unroll
    for (int kk = 0; kk < 2; ++kk) {
      const int kov = (kk * 32 + quad * 8) ^ swz;
      const bf16x8 ap0 = __builtin_bit_cast(bf16x8, pw[0][kk]);
      const bf16x8 ap1 = __builtin_bit_cast(bf16x8, pw[1][kk]);
#pragma unroll
      for (int j = 0; j < 8; ++j) {
        const bf16x8 bv = *(const bf16x8*)&Vs[(j * 16 + lrow) * 64 + kov];
        acco[0][j] = __builtin_amdgcn_mfma_f32_16x16x32_bf16(bv, ap0, acco[0][j], 0, 0, 0);
        acco[1][j] = __builtin_amdgcn_mfma_f32_16x16x32_bf16(bv, ap1, acco[1][j], 0, 0, 0);
      }
    }
    __builtin_amdgcn_s_setprio(0);
    __syncthreads();   // drains K(next) prefetch; PV reads of Vs complete
  }

  // ---- epilogue: stage O tile in LDS, then full-line coalesced stores ----
#pragma unroll
  for (int i = 0; i < 2; ++i) {
    const float inv = 1.0f / l_i[i];
    const int rl = wave * 32 + i * 16 + lrow;        // local row 0..127
#pragma unroll
    for (int j = 0; j < 8; ++j) {
      u16 t4[4];
#pragma unroll
      for (int reg = 0; reg < 4; ++reg) t4[reg] = f2bf(acco[i][j][reg] * inv);
      *(uint2*)&Os[rl * 136 + j * 16 + quad * 4] = *(const uint2*)t4;
    }
  }
  __syncthreads();
  const u16* obase = O + ((size_t)(b * 2048 + qt * 128)) * 4096 + qh * 128;
#pragma unroll
  for (int r = 0; r < 8; ++r) {
    const int chunk = r * 256 + tid;                 // 0..2047 (16B chunks)
    const int row = chunk >> 4, col = (chunk & 15) * 8;
    *(uint4*)(const_cast<u16*>(obase) + (size_t)row * 4096 + col) =
        *(const uint4*)&Os[row * 136 + col];
  }
}

// ---------- launch ----------
extern "C" void kernel_launch(void* const* d_in, const int* in_sizes, int n_in,
                              void* d_out, int out_size, void* d_ws, size_t ws_size,
                              hipStream_t stream) {
  const float* X  = (const float*)d_in[0];
  const float* Wq = (const float*)d_in[2];
  const float* Wk = (const float*)d_in[3];
  const float* Wv = (const float*)d_in[4];
  const float* Wo = (const float*)d_in[5];
  u16* ws = (u16*)d_ws;

  // workspace (u16 elements), ~126 MiB total:
  // Xb(16.7M) | R0(16.7M) | R1(16.7M) | R2(4.2M) | R3(4.2M) | R4(4.2M)
  u16* Xb = ws;
  u16* R0 = Xb + 16777216;
  u16* R1 = R0 + 16777216;
  u16* R2 = R1 + 16777216;
  u16* R3 = R2 + 4194304;
  u16* R4 = R3 + 4194304;
  u16* Qb = R1, *Kb = R3, *Vb = R4, *Vt = R2, *Ob = R0, *WoT = R1;
  u16* WkT = R0;                 // 1024x4096 bf16 (4.2M u16)
  u16* WvT = R0 + 4194304;       // 1024x4096 bf16 (4.2M u16)

  convert_x<<<8192, 256, 0, stream>>>(X, Xb);

  transpose_w<<<dim3(64, 64), 256, 0, stream>>>(Wq, R0, 4096, 4096);
  gemm_bt128<0><<<dim3(32, 32), 256, 0, stream>>>(Xb, R0, Qb, 4096, 4096);

  transpose_w2<<<dim3(16, 64, 2), 256, 0, stream>>>(Wk, WkT, Wv, WvT, 4096, 1024);
  gemm_kv<<<dim3(16, 32), 256, 0, stream>>>(Xb, WkT, WvT, Kb, Vb, 4096, 1024);

  rope_kernel<<<4096, 256, 0, stream>>>(Qb, Kb);
  transpose_v<<<dim3(2, 32, 16), 256, 0, stream>>>(Vb, Vt);

  attn<<<1024, 256, 0, stream>>>(Qb, Kb, Vt, Ob);

  transpose_w<<<dim3(64, 64), 256, 0, stream>>>(Wo, WoT, 4096, 4096);
  gemm_bt128<1><<<dim3(32, 32), 256, 0, stream>>>(Ob, WoT, d_out, 4096, 4096);
}